// Round 3
// baseline (1560.436 us; speedup 1.0000x reference)
//
#include <hip/hip_runtime.h>
#include <hip/hip_bf16.h>

// Problem dims (fixed by the reference)
#define M_TOTAL 8192     // B*T = 4*2048
#define K_DIM   4096     // n (input dim, normalized over)
#define H_DIM   16384    // n_hidden

#define BM 256
#define BN 256
#define BK 64
#define NKT (K_DIM / BK)   // 64 K-tiles

typedef __attribute__((ext_vector_type(8))) short   short8;   // 8 bf16 = 4 VGPRs
typedef __attribute__((ext_vector_type(4))) float   f32x4;
typedef __attribute__((ext_vector_type(8))) unsigned short u16x8;

// RNE float -> bf16
static __device__ __forceinline__ unsigned short f2bf(float f) {
    unsigned int x = __float_as_uint(f);
    x += 0x7fffu + ((x >> 16) & 1u);
    return (unsigned short)(x >> 16);
}

// ---------------------------------------------------------------------------
// Kernel 1: straight cast g (fp32, [M][K]) -> bf16
// ---------------------------------------------------------------------------
__global__ void cast_bf16_kernel(const float* __restrict__ in,
                                 unsigned short* __restrict__ out, long n) {
    long i = ((long)blockIdx.x * blockDim.x + threadIdx.x) * 8;
    if (i >= n) return;
    const float4* p = (const float4*)(in + i);
    float4 a = p[0];
    float4 b = p[1];
    u16x8 o;
    o[0] = f2bf(a.x); o[1] = f2bf(a.y); o[2] = f2bf(a.z); o[3] = f2bf(a.w);
    o[4] = f2bf(b.x); o[5] = f2bf(b.y); o[6] = f2bf(b.z); o[7] = f2bf(b.w);
    *(u16x8*)(out + i) = o;
}

// ---------------------------------------------------------------------------
// Kernel 2: W [K][H] fp32 -> Wt [H][K] bf16  (LDS 64x64 tile transpose)
//           + fused column sum-of-squares into norm2[H]
// ---------------------------------------------------------------------------
__global__ void transpose_norm_kernel(const float* __restrict__ W,
                                      unsigned short* __restrict__ Wt,
                                      float* __restrict__ norm2) {
    __shared__ float tile[64][65];   // +1 pad
    __shared__ float np[64];
    const int h0 = blockIdx.x * 64;
    const int n0 = blockIdx.y * 64;
    const int t  = threadIdx.x;
    const int c  = t & 63;           // fast dim (coalesced global read over h)
    const int r4 = t >> 6;           // 0..3

    if (t < 64) np[t] = 0.f;
    __syncthreads();

    float sq = 0.f;
#pragma unroll
    for (int it = 0; it < 16; ++it) {
        int r = it * 4 + r4;         // n-row within tile
        float v = W[(size_t)(n0 + r) * H_DIM + h0 + c];
        tile[r][c] = v;              // tile[n][h]
        sq += v * v;
    }
    atomicAdd(&np[c], sq);           // LDS atomic, per h-column
    __syncthreads();

    // Write: Wt[h][n], each lane emits 16B (8 bf16 along n)
    const int chunk = t & 7;         // n-chunk (8 elements)
    const int hr    = t >> 3;        // 0..31
#pragma unroll
    for (int it = 0; it < 2; ++it) {
        int hrow = hr + it * 32;
        u16x8 o;
#pragma unroll
        for (int j = 0; j < 8; ++j)
            o[j] = f2bf(tile[chunk * 8 + j][hrow]);
        *(u16x8*)&Wt[(size_t)(h0 + hrow) * K_DIM + n0 + chunk * 8] = o;
    }
    if (t < 64) atomicAdd(&norm2[h0 + t], np[t]);
}

// ---------------------------------------------------------------------------
// Kernel 3: 256x256 / BK=64 / 8-wave bf16 MFMA GEMM, TWO 32-MFMA clusters per
//           K-tile (halved barrier count vs 4-phase), register prefetch:
//
//   regs: aL[4][2] (lo m-half, both ks), aH[4][2] (hi), b[4][2] (persists
//         across both clusters; read once per tile).
//   w1(t): stage A(t+1)->nbuf (4); read b(t) (8) + aH(t) (8) from buf.
//   C1   : barrier; 32 MFMA (aL x b, ks-major); vmcnt(0); barrier.
//          [vmcnt(0) retires A(t+1)'s stages, ~1300cy in flight -> free;
//           the following barrier makes them cross-wave visible]
//   w2(t): stage B(t+1)->nbuf (4); read aL(t+1) (8) from nbuf.
//   C2   : barrier; 32 MFMA (aH x b); vmcnt(0); barrier.  [retires B(t+1)]
//
// Cross-wave stage visibility: every window's ds_reads touch only regions
// whose stages were vmcnt(0)-retired by ALL waves before the immediately
// preceding barrier.  WAR: every overwritten LDS region's last ds_read was
// consumed by MFMAs (lgkm-drained) before a barrier preceding the stage.
// Only b is read in the same window as its consuming cluster (C1); b-reads
// are issued first and C1 is ks-major to bound the exposed LDS latency.
// ---------------------------------------------------------------------------
__global__ __launch_bounds__(512, 2)
void gemm_lse_kernel(const unsigned short* __restrict__ A,
                     const unsigned short* __restrict__ Bt,
                     const float* __restrict__ norm2,
                     float* __restrict__ sums) {
    __shared__ __attribute__((aligned(16))) unsigned short As[2][BM][BK]; // 64 KB
    __shared__ __attribute__((aligned(16))) unsigned short Bs[2][BN][BK]; // 64 KB

    const int tid  = threadIdx.x;
    const int wave = tid >> 6;
    const int lane = tid & 63;
    const int l15  = lane & 15;
    const int quad = lane >> 4;
    const int wm   = wave >> 2;    // 0..1  (m half: 128 rows)
    const int wn   = wave & 3;     // 0..3  (n quarter: 64 cols)

    // ---- block -> (m0,h0): XCD-chunked, 16x16 supertile per XCD ----
    const int bid = blockIdx.x;
    const int xcd = bid & 7;
    const int li  = bid >> 3;                       // 0..255
    const int m0  = ((xcd & 1) * 16 + (li & 15)) * BM;   // mb 0..31
    const int h0  = ((xcd >> 1) * 16 + (li >> 4)) * BN;  // hb 0..63

    // staging: linear LDS dest (base + lane*16), pre-swizzled global source.
    const int ri = lane >> 3;
    const int sc = ((lane & 7) ^ ri) * 8;
    const unsigned short* ag = A  + (size_t)(m0 + wave * 8 + ri) * K_DIM + sc;
    const unsigned short* bg = Bt + (size_t)(h0 + wave * 8 + ri) * K_DIM + sc;

#define STAGE_A(BF_, BASE_, KT_)                                               \
    __builtin_amdgcn_global_load_lds(                                          \
        (const __attribute__((address_space(1))) void*)                        \
            (ag + (size_t)(BASE_) * K_DIM + (KT_) * BK),                       \
        (__attribute__((address_space(3))) void*)&As[BF_][(BASE_) + wave * 8][0], \
        16, 0, 0)
#define STAGE_B(BF_, BASE_, KT_)                                               \
    __builtin_amdgcn_global_load_lds(                                          \
        (const __attribute__((address_space(1))) void*)                        \
            (bg + (size_t)(BASE_) * K_DIM + (KT_) * BK),                       \
        (__attribute__((address_space(3))) void*)&Bs[BF_][(BASE_) + wave * 8][0], \
        16, 0, 0)

    // fragment reads: chunk c = ks*4+quad of row, at swizzled slot c^(row&7)
    const int arow = wm * 128 + l15;
    const int brow = wn * 64 + l15;
    const int sl0  = ((quad)     ^ (l15 & 7)) * 8;
    const int sl1  = ((4 + quad) ^ (l15 & 7)) * 8;

#define LDA(D_, BF_, FM_, KS_) D_ = *(const short8*)&As[BF_][arow + (FM_) * 16][(KS_) ? sl1 : sl0]
#define LDB(D_, BF_, FN_, KS_) D_ = *(const short8*)&Bs[BF_][brow + (FN_) * 16][(KS_) ? sl1 : sl0]

    f32x4 acc[8][4];
#pragma unroll
    for (int i = 0; i < 8; ++i)
#pragma unroll
        for (int j = 0; j < 4; ++j)
            acc[i][j] = (f32x4){0.f, 0.f, 0.f, 0.f};

    short8 aL[4][2], aH[4][2], b[4][2];

#define CLUSTER(SA_, FB_)                                                      \
    __builtin_amdgcn_s_barrier();                                              \
    __builtin_amdgcn_s_setprio(1);                                             \
    _Pragma("unroll")                                                          \
    for (int ks = 0; ks < 2; ++ks)                                             \
        _Pragma("unroll")                                                      \
        for (int fm = 0; fm < 4; ++fm)                                         \
            _Pragma("unroll")                                                  \
            for (int fn = 0; fn < 4; ++fn)                                     \
                acc[(FB_) + fm][fn] = __builtin_amdgcn_mfma_f32_16x16x32_bf16( \
                    SA_[fm][ks], b[fn][ks], acc[(FB_) + fm][fn], 0, 0, 0);     \
    __builtin_amdgcn_s_setprio(0);                                             \
    asm volatile("s_waitcnt vmcnt(0)" ::: "memory");                           \
    __builtin_amdgcn_s_barrier()

    // ---- prologue: stage A(0)+B(0) into buf0, drain, prefetch aL(0) -------
    STAGE_A(0, 0, 0);   STAGE_A(0, 64, 0);
    STAGE_A(0, 128, 0); STAGE_A(0, 192, 0);
    STAGE_B(0, 0, 0);   STAGE_B(0, 64, 0);
    STAGE_B(0, 128, 0); STAGE_B(0, 192, 0);
    asm volatile("s_waitcnt vmcnt(0)" ::: "memory");
    __builtin_amdgcn_s_barrier();

    LDA(aL[0][0], 0, 0, 0); LDA(aL[1][0], 0, 1, 0);
    LDA(aL[2][0], 0, 2, 0); LDA(aL[3][0], 0, 3, 0);
    LDA(aL[0][1], 0, 0, 1); LDA(aL[1][1], 0, 1, 1);
    LDA(aL[2][1], 0, 2, 1); LDA(aL[3][1], 0, 3, 1);

#pragma unroll 2
    for (int t = 0; t < NKT; ++t) {
        const int buf  = t & 1;
        const int nbuf = buf ^ 1;

        // ---- w1: stage A(t+1); read b(t) (consumed by C1!) + aH(t) --------
        if (t < NKT - 1) {
            STAGE_A(nbuf, 0, t + 1);   STAGE_A(nbuf, 64, t + 1);
            STAGE_A(nbuf, 128, t + 1); STAGE_A(nbuf, 192, t + 1);
        }
        LDB(b[0][0], buf, 0, 0); LDB(b[1][0], buf, 1, 0);   // ks0 first: C1
        LDB(b[2][0], buf, 2, 0); LDB(b[3][0], buf, 3, 0);   // is ks-major
        LDB(b[0][1], buf, 0, 1); LDB(b[1][1], buf, 1, 1);
        LDB(b[2][1], buf, 2, 1); LDB(b[3][1], buf, 3, 1);
        LDA(aH[0][0], buf, 4, 0); LDA(aH[1][0], buf, 5, 0);
        LDA(aH[2][0], buf, 6, 0); LDA(aH[3][0], buf, 7, 0);
        LDA(aH[0][1], buf, 4, 1); LDA(aH[1][1], buf, 5, 1);
        LDA(aH[2][1], buf, 6, 1); LDA(aH[3][1], buf, 7, 1);

        // ---- C1: lo m-half; ends vmcnt(0) [retires A(t+1)] + barrier ------
        CLUSTER(aL, 0);

        // ---- w2: stage B(t+1); prefetch aL(t+1) from nbuf -----------------
        if (t < NKT - 1) {
            STAGE_B(nbuf, 0, t + 1);   STAGE_B(nbuf, 64, t + 1);
            STAGE_B(nbuf, 128, t + 1); STAGE_B(nbuf, 192, t + 1);
            LDA(aL[0][0], nbuf, 0, 0); LDA(aL[1][0], nbuf, 1, 0);
            LDA(aL[2][0], nbuf, 2, 0); LDA(aL[3][0], nbuf, 3, 0);
            LDA(aL[0][1], nbuf, 0, 1); LDA(aL[1][1], nbuf, 1, 1);
            LDA(aL[2][1], nbuf, 2, 1); LDA(aL[3][1], nbuf, 3, 1);
        }

        // ---- C2: hi m-half; ends vmcnt(0) [retires B(t+1)] + barrier ------
        CLUSTER(aH, 4);
    }

    // ---- epilogue. C/D layout: row = quad*4 + reg, col = lane&15 ----
    float rn[4];
#pragma unroll
    for (int fn = 0; fn < 4; ++fn)
        rn[fn] = rsqrtf(norm2[h0 + wn * 64 + fn * 16 + l15]);

#pragma unroll
    for (int fm = 0; fm < 8; ++fm) {
#pragma unroll
        for (int r2 = 0; r2 < 4; ++r2) {
            float s = 0.f;
#pragma unroll
            for (int fn = 0; fn < 4; ++fn)
                s += __expf(acc[fm][fn][r2] * rn[fn]);
            s += __shfl_xor(s, 1);
            s += __shfl_xor(s, 2);
            s += __shfl_xor(s, 4);
            s += __shfl_xor(s, 8);
            if (l15 == 0)
                atomicAdd(&sums[m0 + wm * 128 + fm * 16 + quad * 4 + r2], s);
        }
    }
#undef STAGE_A
#undef STAGE_B
#undef LDA
#undef LDB
#undef CLUSTER
}

// ---------------------------------------------------------------------------
// Kernel 4: out[m] = log(sums[m])   (BETA = 1)
// ---------------------------------------------------------------------------
__global__ void finalize_kernel(const float* __restrict__ sums,
                                float* __restrict__ out, int n) {
    int i = blockIdx.x * blockDim.x + threadIdx.x;
    if (i < n) out[i] = logf(sums[i]);
}

// ---------------------------------------------------------------------------
extern "C" void kernel_launch(void* const* d_in, const int* in_sizes, int n_in,
                              void* d_out, int out_size, void* d_ws, size_t ws_size,
                              hipStream_t stream) {
    const float* g = (const float*)d_in[0];   // [4,2048,4096] fp32
    const float* W = (const float*)d_in[1];   // [4096,16384] fp32
    float* out = (float*)d_out;               // [8192] fp32

    char* ws = (char*)d_ws;
    unsigned short* gbf   = (unsigned short*)ws;                              // 64 MB
    unsigned short* wt    = (unsigned short*)(ws + (size_t)67108864);         // 128 MB
    float*          norm2 = (float*)(ws + (size_t)67108864 + 134217728);      // 64 KB
    float*          sums  = (float*)(ws + (size_t)67108864 + 134217728 + 65536); // 32 KB

    hipMemsetAsync(norm2, 0, (H_DIM + M_TOTAL) * sizeof(float), stream);

    cast_bf16_kernel<<<(M_TOTAL * (long)K_DIM) / (256 * 8), 256, 0, stream>>>(
        g, gbf, (long)M_TOTAL * K_DIM);

    transpose_norm_kernel<<<dim3(H_DIM / 64, K_DIM / 64), 256, 0, stream>>>(
        W, wt, norm2);

    gemm_lse_kernel<<<(H_DIM / BN) * (M_TOTAL / BM), 512, 0, stream>>>(
        gbf, wt, norm2, sums);

    finalize_kernel<<<(M_TOTAL + 255) / 256, 256, 0, stream>>>(sums, out, M_TOTAL);
}

// Round 4
// 1496.281 us; speedup vs baseline: 1.0429x; 1.0429x over previous
//
#include <hip/hip_runtime.h>
#include <hip/hip_bf16.h>

// Problem dims (fixed by the reference)
#define M_TOTAL 8192     // B*T = 4*2048
#define K_DIM   4096     // n (input dim, normalized over)
#define H_DIM   16384    // n_hidden

#define BM 256
#define BN 256
#define BK 64
#define NKT (K_DIM / BK)   // 64 K-tiles

typedef __attribute__((ext_vector_type(8))) short   short8;   // 8 bf16 = 4 VGPRs
typedef __attribute__((ext_vector_type(4))) float   f32x4;
typedef __attribute__((ext_vector_type(8))) unsigned short u16x8;

// RNE float -> bf16
static __device__ __forceinline__ unsigned short f2bf(float f) {
    unsigned int x = __float_as_uint(f);
    x += 0x7fffu + ((x >> 16) & 1u);
    return (unsigned short)(x >> 16);
}

// ---------------------------------------------------------------------------
// Kernel 1: straight cast g (fp32, [M][K]) -> bf16
// ---------------------------------------------------------------------------
__global__ void cast_bf16_kernel(const float* __restrict__ in,
                                 unsigned short* __restrict__ out, long n) {
    long i = ((long)blockIdx.x * blockDim.x + threadIdx.x) * 8;
    if (i >= n) return;
    const float4* p = (const float4*)(in + i);
    float4 a = p[0];
    float4 b = p[1];
    u16x8 o;
    o[0] = f2bf(a.x); o[1] = f2bf(a.y); o[2] = f2bf(a.z); o[3] = f2bf(a.w);
    o[4] = f2bf(b.x); o[5] = f2bf(b.y); o[6] = f2bf(b.z); o[7] = f2bf(b.w);
    *(u16x8*)(out + i) = o;
}

// ---------------------------------------------------------------------------
// Kernel 2: W [K][H] fp32 -> Wt [H][K] bf16  (LDS 64x64 tile transpose)
//           + fused column sum-of-squares into norm2[H]
// ---------------------------------------------------------------------------
__global__ void transpose_norm_kernel(const float* __restrict__ W,
                                      unsigned short* __restrict__ Wt,
                                      float* __restrict__ norm2) {
    __shared__ float tile[64][65];   // +1 pad
    __shared__ float np[64];
    const int h0 = blockIdx.x * 64;
    const int n0 = blockIdx.y * 64;
    const int t  = threadIdx.x;
    const int c  = t & 63;           // fast dim (coalesced global read over h)
    const int r4 = t >> 6;           // 0..3

    if (t < 64) np[t] = 0.f;
    __syncthreads();

    float sq = 0.f;
#pragma unroll
    for (int it = 0; it < 16; ++it) {
        int r = it * 4 + r4;         // n-row within tile
        float v = W[(size_t)(n0 + r) * H_DIM + h0 + c];
        tile[r][c] = v;              // tile[n][h]
        sq += v * v;
    }
    atomicAdd(&np[c], sq);           // LDS atomic, per h-column
    __syncthreads();

    // Write: Wt[h][n], each lane emits 16B (8 bf16 along n)
    const int chunk = t & 7;         // n-chunk (8 elements)
    const int hr    = t >> 3;        // 0..31
#pragma unroll
    for (int it = 0; it < 2; ++it) {
        int hrow = hr + it * 32;
        u16x8 o;
#pragma unroll
        for (int j = 0; j < 8; ++j)
            o[j] = f2bf(tile[chunk * 8 + j][hrow]);
        *(u16x8*)&Wt[(size_t)(h0 + hrow) * K_DIM + n0 + chunk * 8] = o;
    }
    if (t < 64) atomicAdd(&norm2[h0 + t], np[t]);
}

// ---------------------------------------------------------------------------
// Kernel 3: 256x256 / BK=64 / 8-wave bf16 MFMA GEMM.  4 phases per K-tile,
//   ONE barrier per phase, and ALL memory work (global_load_lds stages +
//   ds_read fragment prefetch for the NEXT phase) issued INSIDE the
//   barrier-protected cluster region so it overlaps the 16 MFMAs (which
//   consume only registers).  Counted vmcnt in the gaps; never 0 mid-loop.
//
//   Frag sets: ph1 MFMA(sa0=A.lo.ks0, sb0=B.ks0)   reads: sa1<-A.lo.ks1,
//              sb1<-B.ks1            stage: A(t+1)h1 -> nbuf
//              ph2 MFMA(sa1, sb1)    reads: sa0<-A.hi.ks0
//              ph3 MFMA(sa0, sb0)    reads: sa1<-A.hi.ks1   stage: A(t+2)h0
//              ph4 MFMA(sa1, sb1)    reads: sa0<-A(t+1).lo.ks0,
//                                           sb0<-B(t+1).ks0 [from nbuf]
//                                    stage: B(t+2) -> buf
//   Wait ledger (steady, per wave, oldest->newest):
//     ph1 gap: [Ah1(t) 2 | Ah0(t+1) 2, B(t+1) 4] -> vmcnt(6) retires Ah1(t)
//              (needed by ph2 reads); tail t==NKT-1: vmcnt(0)
//     ph4 gap: [Ah0(t+1) 2, B(t+1) 4 | Ah1(t+1) 2, Ah0(t+2) 2] -> vmcnt(4)
//              retires Ah0(t+1)+B(t+1) (needed by ph4 reads);
//              tail t>=NKT-2: vmcnt(2) (only 8 outstanding then)
//   WAR audit: every LDS overwrite is preceded by a barrier that is preceded
//   by the lgkm-drain of that region's last ds_read (drain happens at the
//   consuming MFMA cluster, >=1 phase-barrier before the stage).
//   Visibility audit: every ds_read's source region was vmcnt-retired by all
//   waves before the immediately preceding phase barrier.
// ---------------------------------------------------------------------------
__global__ __launch_bounds__(512, 2)
void gemm_lse_kernel(const unsigned short* __restrict__ A,
                     const unsigned short* __restrict__ Bt,
                     const float* __restrict__ norm2,
                     float* __restrict__ sums) {
    __shared__ __attribute__((aligned(16))) unsigned short As[2][BM][BK]; // 64 KB
    __shared__ __attribute__((aligned(16))) unsigned short Bs[2][BN][BK]; // 64 KB

    const int tid  = threadIdx.x;
    const int wave = tid >> 6;
    const int lane = tid & 63;
    const int l15  = lane & 15;
    const int quad = lane >> 4;
    const int wm   = wave >> 2;    // 0..1  (m half: 128 rows)
    const int wn   = wave & 3;     // 0..3  (n quarter: 64 cols)

    // ---- block -> (m0,h0): XCD-chunked, 16x16 supertile per XCD ----
    const int bid = blockIdx.x;
    const int xcd = bid & 7;
    const int li  = bid >> 3;                       // 0..255
    const int m0  = ((xcd & 1) * 16 + (li & 15)) * BM;   // mb 0..31
    const int h0  = ((xcd >> 1) * 16 + (li >> 4)) * BN;  // hb 0..63

    // staging: linear LDS dest (base + lane*16), pre-swizzled global source.
    const int ri = lane >> 3;
    const int sc = ((lane & 7) ^ ri) * 8;
    const unsigned short* ag = A  + (size_t)(m0 + wave * 8 + ri) * K_DIM + sc;
    const unsigned short* bg = Bt + (size_t)(h0 + wave * 8 + ri) * K_DIM + sc;

#define STAGE_A(BF_, BASE_, KT_)                                               \
    __builtin_amdgcn_global_load_lds(                                          \
        (const __attribute__((address_space(1))) void*)                        \
            (ag + (size_t)(BASE_) * K_DIM + (KT_) * BK),                       \
        (__attribute__((address_space(3))) void*)&As[BF_][(BASE_) + wave * 8][0], \
        16, 0, 0)
#define STAGE_B(BF_, BASE_, KT_)                                               \
    __builtin_amdgcn_global_load_lds(                                          \
        (const __attribute__((address_space(1))) void*)                        \
            (bg + (size_t)(BASE_) * K_DIM + (KT_) * BK),                       \
        (__attribute__((address_space(3))) void*)&Bs[BF_][(BASE_) + wave * 8][0], \
        16, 0, 0)

    // fragment reads: chunk c = ks*4+quad of row, at swizzled slot c^(row&7)
    const int arow = wm * 128 + l15;
    const int brow = wn * 64 + l15;
    const int sl0  = ((quad)     ^ (l15 & 7)) * 8;
    const int sl1  = ((4 + quad) ^ (l15 & 7)) * 8;

#define LDA(D_, BF_, FM_, KS_) D_ = *(const short8*)&As[BF_][arow + (FM_) * 16][(KS_) ? sl1 : sl0]
#define LDB(D_, BF_, FN_, KS_) D_ = *(const short8*)&Bs[BF_][brow + (FN_) * 16][(KS_) ? sl1 : sl0]

    f32x4 acc[8][4];
#pragma unroll
    for (int i = 0; i < 8; ++i)
#pragma unroll
        for (int j = 0; j < 4; ++j)
            acc[i][j] = (f32x4){0.f, 0.f, 0.f, 0.f};

    short8 sa0[4], sb0[4], sa1[4], sb1[4];

#define MFMA16(FB_, SA_, SB_)                                                  \
    _Pragma("unroll")                                                          \
    for (int fm = 0; fm < 4; ++fm)                                             \
        _Pragma("unroll")                                                      \
        for (int fn = 0; fn < 4; ++fn)                                         \
            acc[(FB_) + fm][fn] = __builtin_amdgcn_mfma_f32_16x16x32_bf16(     \
                SA_[fm], SB_[fn], acc[(FB_) + fm][fn], 0, 0, 0)

    // ---- prologue: A(0) full, B(0), A(1)h0, B(1); retire A(0)+B(0) --------
    STAGE_A(0, 0, 0);   STAGE_A(0, 128, 0);    // A0 h0
    STAGE_A(0, 64, 0);  STAGE_A(0, 192, 0);    // A0 h1
    STAGE_B(0, 0, 0);   STAGE_B(0, 64, 0);     // B0
    STAGE_B(0, 128, 0); STAGE_B(0, 192, 0);
    STAGE_A(1, 0, 1);   STAGE_A(1, 128, 1);    // A1 h0
    STAGE_B(1, 0, 1);   STAGE_B(1, 64, 1);     // B1
    STAGE_B(1, 128, 1); STAGE_B(1, 192, 1);
    asm volatile("s_waitcnt vmcnt(6)" ::: "memory");
    __builtin_amdgcn_s_barrier();

    // pre-loop prefetch: S0 <- {A(0) lo ks0, B(0) ks0}
    LDA(sa0[0], 0, 0, 0); LDA(sa0[1], 0, 1, 0);
    LDA(sa0[2], 0, 2, 0); LDA(sa0[3], 0, 3, 0);
    LDB(sb0[0], 0, 0, 0); LDB(sb0[1], 0, 1, 0);
    LDB(sb0[2], 0, 2, 0); LDB(sb0[3], 0, 3, 0);

#pragma unroll 2
    for (int t = 0; t < NKT; ++t) {
        const int buf  = t & 1;
        const int nbuf = buf ^ 1;

        // ==== ph1: gap wait; cluster = {stage A(t+1)h1, read S1, MFMA S0} ==
        if (t < NKT - 1) { asm volatile("s_waitcnt vmcnt(6)" ::: "memory"); }
        else             { asm volatile("s_waitcnt vmcnt(0)" ::: "memory"); }
        __builtin_amdgcn_s_barrier();
        __builtin_amdgcn_s_setprio(1);
        if (t < NKT - 1) { STAGE_A(nbuf, 64, t + 1); STAGE_A(nbuf, 192, t + 1); }
        LDA(sa1[0], buf, 0, 1); LDA(sa1[1], buf, 1, 1);   // A lo ks1
        LDA(sa1[2], buf, 2, 1); LDA(sa1[3], buf, 3, 1);
        LDB(sb1[0], buf, 0, 1); LDB(sb1[1], buf, 1, 1);   // B ks1
        LDB(sb1[2], buf, 2, 1); LDB(sb1[3], buf, 3, 1);
        MFMA16(0, sa0, sb0);
        __builtin_amdgcn_s_setprio(0);

        // ==== ph2: cluster = {read S0.A <- A hi ks0, MFMA S1} ==============
        __builtin_amdgcn_s_barrier();
        __builtin_amdgcn_s_setprio(1);
        LDA(sa0[0], buf, 4, 0); LDA(sa0[1], buf, 5, 0);
        LDA(sa0[2], buf, 6, 0); LDA(sa0[3], buf, 7, 0);
        MFMA16(0, sa1, sb1);
        __builtin_amdgcn_s_setprio(0);

        // ==== ph3: cluster = {stage A(t+2)h0, read S1.A <- A hi ks1, MFMA S0}
        __builtin_amdgcn_s_barrier();
        __builtin_amdgcn_s_setprio(1);
        if (t < NKT - 2) { STAGE_A(buf, 0, t + 2); STAGE_A(buf, 128, t + 2); }
        LDA(sa1[0], buf, 4, 1); LDA(sa1[1], buf, 5, 1);
        LDA(sa1[2], buf, 6, 1); LDA(sa1[3], buf, 7, 1);
        MFMA16(4, sa0, sb0);
        __builtin_amdgcn_s_setprio(0);

        // ==== ph4: gap wait; cluster = {stage B(t+2), read S0 <- next tile,
        //                                MFMA S1} ===========================
        if (t < NKT - 2) { asm volatile("s_waitcnt vmcnt(4)" ::: "memory"); }
        else             { asm volatile("s_waitcnt vmcnt(2)" ::: "memory"); }
        __builtin_amdgcn_s_barrier();
        __builtin_amdgcn_s_setprio(1);
        if (t < NKT - 2) {
            STAGE_B(buf, 0, t + 2);   STAGE_B(buf, 64, t + 2);
            STAGE_B(buf, 128, t + 2); STAGE_B(buf, 192, t + 2);
        }
        if (t < NKT - 1) {
            LDA(sa0[0], nbuf, 0, 0); LDA(sa0[1], nbuf, 1, 0); // A(t+1) lo ks0
            LDA(sa0[2], nbuf, 2, 0); LDA(sa0[3], nbuf, 3, 0);
            LDB(sb0[0], nbuf, 0, 0); LDB(sb0[1], nbuf, 1, 0); // B(t+1) ks0
            LDB(sb0[2], nbuf, 2, 0); LDB(sb0[3], nbuf, 3, 0);
        }
        MFMA16(4, sa1, sb1);
        __builtin_amdgcn_s_setprio(0);
    }

    // ---- epilogue. C/D layout: row = quad*4 + reg, col = lane&15 ----
    float rn[4];
#pragma unroll
    for (int fn = 0; fn < 4; ++fn)
        rn[fn] = rsqrtf(norm2[h0 + wn * 64 + fn * 16 + l15]);

#pragma unroll
    for (int fm = 0; fm < 8; ++fm) {
#pragma unroll
        for (int r2 = 0; r2 < 4; ++r2) {
            float s = 0.f;
#pragma unroll
            for (int fn = 0; fn < 4; ++fn)
                s += __expf(acc[fm][fn][r2] * rn[fn]);
            s += __shfl_xor(s, 1);
            s += __shfl_xor(s, 2);
            s += __shfl_xor(s, 4);
            s += __shfl_xor(s, 8);
            if (l15 == 0)
                atomicAdd(&sums[m0 + wm * 128 + fm * 16 + quad * 4 + r2], s);
        }
    }
#undef STAGE_A
#undef STAGE_B
#undef LDA
#undef LDB
#undef MFMA16
}

// ---------------------------------------------------------------------------
// Kernel 4: out[m] = log(sums[m])   (BETA = 1)
// ---------------------------------------------------------------------------
__global__ void finalize_kernel(const float* __restrict__ sums,
                                float* __restrict__ out, int n) {
    int i = blockIdx.x * blockDim.x + threadIdx.x;
    if (i < n) out[i] = logf(sums[i]);
}

// ---------------------------------------------------------------------------
extern "C" void kernel_launch(void* const* d_in, const int* in_sizes, int n_in,
                              void* d_out, int out_size, void* d_ws, size_t ws_size,
                              hipStream_t stream) {
    const float* g = (const float*)d_in[0];   // [4,2048,4096] fp32
    const float* W = (const float*)d_in[1];   // [4096,16384] fp32
    float* out = (float*)d_out;               // [8192] fp32

    char* ws = (char*)d_ws;
    unsigned short* gbf   = (unsigned short*)ws;                              // 64 MB
    unsigned short* wt    = (unsigned short*)(ws + (size_t)67108864);         // 128 MB
    float*          norm2 = (float*)(ws + (size_t)67108864 + 134217728);      // 64 KB
    float*          sums  = (float*)(ws + (size_t)67108864 + 134217728 + 65536); // 32 KB

    hipMemsetAsync(norm2, 0, (H_DIM + M_TOTAL) * sizeof(float), stream);

    cast_bf16_kernel<<<(M_TOTAL * (long)K_DIM) / (256 * 8), 256, 0, stream>>>(
        g, gbf, (long)M_TOTAL * K_DIM);

    transpose_norm_kernel<<<dim3(H_DIM / 64, K_DIM / 64), 256, 0, stream>>>(
        W, wt, norm2);

    gemm_lse_kernel<<<(H_DIM / BN) * (M_TOTAL / BM), 512, 0, stream>>>(
        gbf, wt, norm2, sums);

    finalize_kernel<<<(M_TOTAL + 255) / 256, 256, 0, stream>>>(sums, out, M_TOTAL);
}